// Round 1
// baseline (155.846 us; speedup 1.0000x reference)
//
#include <hip/hip_runtime.h>

// RandomShift: reflect-mode variable padding gather.
// in_: (N,T,F) fp32, in_lens: (N,) i32, pad: (2,N) i32
// out: (N,TP,F) fp32 followed by out_lens (N,) stored as fp32.
//
// Structure: grid = (TP/24, N). blockIdx.y = n so pad0/pad1/len are
// wave-uniform -> compiler emits s_load once per block (kills the 3
// per-thread dword loads of the 1D version). Each wave owns 6 consecutive
// rows; fast path batches 6 independent 1KB loads before the 6 stores
// (deep MLP), slow path handles the valid/invalid boundary per-row.
// Stores are nontemporal: 107 MB streaming output must not evict the
// L3-resident 64 MB input.

#define N_  16
#define T_  4096
#define F_  256
#define TP_ 6552          // T + 2*int(0.3*T)
#define F4_ (F_ / 4)      // 64 float4 per row == one wave's lanes

#define RPW 6             // rows per wave
#define RPB (RPW * 4)     // rows per block (4 waves) = 24; 6552 = 24*273
#define GX  (TP_ / RPB)   // 273

typedef float v4f __attribute__((ext_vector_type(4)));

__global__ __launch_bounds__(256) void random_shift_kernel(
    const float* __restrict__ in_,
    const int*   __restrict__ in_lens,
    const int*   __restrict__ pad,
    float*       __restrict__ out)
{
    const int n = blockIdx.y;                 // uniform -> SGPR
    const int pad0 = pad[n];                  // s_load
    const int len  = in_lens[n];              // s_load
    const int out_len = len + pad0 + pad[N_ + n];

    // out_lens tail (16 floats after the (N,TP,F) block)
    if (blockIdx.x == 0 && threadIdx.x == 0)
        out[(size_t)N_ * TP_ * F_ + n] = (float)out_len;

    const int lane = threadIdx.x & 63;
    const int wave = threadIdx.x >> 6;
    const int t0   = blockIdx.x * RPB + wave * RPW;

    const v4f* __restrict__ inb  = (const v4f*)(in_ + (size_t)n * T_ * F_);
    v4f*       __restrict__ outb = (v4f*)(out + (size_t)n * TP_ * F_);

    // src is provably in [0, T-1] for all three pieces (pad_i <= floor(0.3*len)),
    // so no clamp needed.
    if (t0 + RPW <= out_len) {
        // Fast path: all 6 rows valid. Batch loads, then stores.
        v4f vv[RPW];
        #pragma unroll
        for (int r = 0; r < RPW; ++r) {
            const int t = t0 + r;
            const int src = (t < pad0)       ? (pad0 - t)
                          : (t < pad0 + len) ? (t - pad0)
                          :                    (2 * len + pad0 - t - 2);
            vv[r] = inb[(size_t)src * F4_ + lane];
        }
        #pragma unroll
        for (int r = 0; r < RPW; ++r)
            __builtin_nontemporal_store(vv[r], &outb[(size_t)(t0 + r) * F4_ + lane]);
    } else if (t0 >= out_len) {
        // Fully invalid: zero-fill 6 rows.
        const v4f z = (v4f){0.f, 0.f, 0.f, 0.f};
        #pragma unroll
        for (int r = 0; r < RPW; ++r)
            __builtin_nontemporal_store(z, &outb[(size_t)(t0 + r) * F4_ + lane]);
    } else {
        // Boundary wave: per-row predicate (wave-uniform branch).
        #pragma unroll
        for (int r = 0; r < RPW; ++r) {
            const int t = t0 + r;
            v4f v = (v4f){0.f, 0.f, 0.f, 0.f};
            if (t < out_len) {
                const int src = (t < pad0)       ? (pad0 - t)
                              : (t < pad0 + len) ? (t - pad0)
                              :                    (2 * len + pad0 - t - 2);
                v = inb[(size_t)src * F4_ + lane];
            }
            __builtin_nontemporal_store(v, &outb[(size_t)t * F4_ + lane]);
        }
    }
}

extern "C" void kernel_launch(void* const* d_in, const int* in_sizes, int n_in,
                              void* d_out, int out_size, void* d_ws, size_t ws_size,
                              hipStream_t stream) {
    const float* in_     = (const float*)d_in[0];
    const int*   in_lens = (const int*)d_in[1];
    const int*   pad     = (const int*)d_in[2];
    float*       out     = (float*)d_out;

    dim3 grid(GX, N_);       // 273 x 16 blocks, 256 threads each
    random_shift_kernel<<<grid, dim3(256), 0, stream>>>(in_, in_lens, pad, out);
}

// Round 2
// 151.579 us; speedup vs baseline: 1.0282x; 1.0282x over previous
//
#include <hip/hip_runtime.h>

// RandomShift: reflect-mode variable padding gather.
// in_: (N,T,F) fp32, in_lens: (N,) i32, pad: (2,N) i32
// out: (N,TP,F) fp32 followed by out_lens (N,) stored as fp32.
//
// Structure: grid = (TP/24, N). blockIdx.y = n so pad0/pad1/len are
// wave-uniform -> s_load once per block. Each wave owns 6 consecutive
// rows; fast path batches 6 independent 1KB loads before the 6 stores.
// Stores are PLAIN (round-1 A/B: nontemporal stores cost ~7 us -- gfx950
// write path is fastest through the normal L2 write-combining route, same
// as the 83%-of-peak fillBuffer kernel).

#define N_  16
#define T_  4096
#define F_  256
#define TP_ 6552          // T + 2*int(0.3*T)
#define F4_ (F_ / 4)      // 64 float4 per row == one wave's lanes

#define RPW 6             // rows per wave
#define RPB (RPW * 4)     // rows per block (4 waves) = 24; 6552 = 24*273
#define GX  (TP_ / RPB)   // 273

typedef float v4f __attribute__((ext_vector_type(4)));

__global__ __launch_bounds__(256) void random_shift_kernel(
    const float* __restrict__ in_,
    const int*   __restrict__ in_lens,
    const int*   __restrict__ pad,
    float*       __restrict__ out)
{
    const int n = blockIdx.y;                 // uniform -> SGPR
    const int pad0 = pad[n];                  // s_load
    const int len  = in_lens[n];              // s_load
    const int out_len = len + pad0 + pad[N_ + n];

    // out_lens tail (16 floats after the (N,TP,F) block)
    if (blockIdx.x == 0 && threadIdx.x == 0)
        out[(size_t)N_ * TP_ * F_ + n] = (float)out_len;

    const int lane = threadIdx.x & 63;
    const int wave = threadIdx.x >> 6;
    const int t0   = blockIdx.x * RPB + wave * RPW;

    const v4f* __restrict__ inb  = (const v4f*)(in_ + (size_t)n * T_ * F_);
    v4f*       __restrict__ outb = (v4f*)(out + (size_t)n * TP_ * F_);

    // src is provably in [0, T-1] for all three pieces (pad_i <= floor(0.3*len)),
    // so no clamp needed.
    if (t0 + RPW <= out_len) {
        // Fast path: all 6 rows valid. Batch loads, then stores.
        v4f vv[RPW];
        #pragma unroll
        for (int r = 0; r < RPW; ++r) {
            const int t = t0 + r;
            const int src = (t < pad0)       ? (pad0 - t)
                          : (t < pad0 + len) ? (t - pad0)
                          :                    (2 * len + pad0 - t - 2);
            vv[r] = inb[(size_t)src * F4_ + lane];
        }
        #pragma unroll
        for (int r = 0; r < RPW; ++r)
            outb[(size_t)(t0 + r) * F4_ + lane] = vv[r];
    } else if (t0 >= out_len) {
        // Fully invalid: zero-fill 6 rows.
        const v4f z = (v4f){0.f, 0.f, 0.f, 0.f};
        #pragma unroll
        for (int r = 0; r < RPW; ++r)
            outb[(size_t)(t0 + r) * F4_ + lane] = z;
    } else {
        // Boundary wave: per-row predicate (wave-uniform branch).
        #pragma unroll
        for (int r = 0; r < RPW; ++r) {
            const int t = t0 + r;
            v4f v = (v4f){0.f, 0.f, 0.f, 0.f};
            if (t < out_len) {
                const int src = (t < pad0)       ? (pad0 - t)
                              : (t < pad0 + len) ? (t - pad0)
                              :                    (2 * len + pad0 - t - 2);
                v = inb[(size_t)src * F4_ + lane];
            }
            outb[(size_t)t * F4_ + lane] = v;
        }
    }
}

extern "C" void kernel_launch(void* const* d_in, const int* in_sizes, int n_in,
                              void* d_out, int out_size, void* d_ws, size_t ws_size,
                              hipStream_t stream) {
    const float* in_     = (const float*)d_in[0];
    const int*   in_lens = (const int*)d_in[1];
    const int*   pad     = (const int*)d_in[2];
    float*       out     = (float*)d_out;

    dim3 grid(GX, N_);       // 273 x 16 blocks, 256 threads each
    random_shift_kernel<<<grid, dim3(256), 0, stream>>>(in_, in_lens, pad, out);
}